// Round 1
// baseline (1369.613 us; speedup 1.0000x reference)
//
#include <hip/hip_runtime.h>
#include <math.h>

// Problem constants
#define BN 32
#define CC 8
#define HH 300
#define WW 300
#define HW 90000            // 300*300
#define NPX (BN * HW)       // per-channel pixel count for BN: 32*90000 = 2,880,000

// Tiling for fused kernel
#define TH 20
#define TW 20
#define NTY 15
#define NTX 15

// Workspace layout (float offsets)
#define OFF_P5   0              // [32][8][60*60]  = 921600 floats
#define OFF_P10  921600         // [32][8][30*30]  = 230400
#define OFF_P15  1152000        // [32][8][20*20]  = 102400
#define OFF_WA   1254400        // [3][16][8][9]   = 3456   (w5/w10/w15 rearranged [kk][ci][o][tap])
#define OFF_GWA  1257856        // [24][8][9]      = 1728   (gw rearranged [ci24][o][tap])
#define OFF_MWA  1259584        // [24][8][9]      = 1728
#define FLOATS_END 1261312
#define STAT_BYTE_OFF  5045248  // = FLOATS_END*4, 8B aligned; [16][64] doubles = 8192 B
#define SS_BYTE_OFF    5053440  // 16 floats: scale[8], shift[8]

// ---------------------------------------------------------------------------
// K0: rearrange weights for wave-uniform (SGPR) access + zero BN stat bins
// ---------------------------------------------------------------------------
__global__ void k_setup(const float* __restrict__ w5, const float* __restrict__ w10,
                        const float* __restrict__ w15, const float* __restrict__ gw,
                        const float* __restrict__ mw, float* __restrict__ ws,
                        double* __restrict__ stats) {
    int t = threadIdx.x;
    // wA[kk][ci][o][tap] <- wK[o][ci][tap]   (wK shape (8,16,3,3))
    for (int idx = t; idx < 3 * 16 * 8 * 9; idx += 256) {
        int kk = idx / 1152;
        int rem = idx % 1152;
        int ci = rem / 72;
        int r2 = rem % 72;
        int o = r2 / 9;
        int tap = r2 % 9;
        const float* src = (kk == 0) ? w5 : ((kk == 1) ? w10 : w15);
        ws[OFF_WA + idx] = src[(o * 16 + ci) * 9 + tap];
    }
    // gwA/mwA[kc][o][tap] <- gw[o][kc][tap]  (gw shape (8,24,3,3))
    for (int idx = t; idx < 24 * 72; idx += 256) {
        int kc = idx / 72;
        int r2 = idx % 72;
        int o = r2 / 9;
        int tap = r2 % 9;
        ws[OFF_GWA + idx] = gw[(o * 24 + kc) * 9 + tap];
        ws[OFF_MWA + idx] = mw[(o * 24 + kc) * 9 + tap];
    }
    // zero the 16x64 double stat bins (ws is poisoned 0xAA before every call)
    for (int idx = t; idx < 16 * 64; idx += 256) stats[idx] = 0.0;
}

// ---------------------------------------------------------------------------
// K1: adaptive-avg-pool to 60x60 (k=5), then derive 30x30 (k=10), 20x20 (k=15)
// one block per (b,c) plane
// ---------------------------------------------------------------------------
__global__ void k_pool(const float* __restrict__ x, float* __restrict__ ws) {
    int bc = blockIdx.x;  // 0..255 = b*8+c
    const float* xp = x + (size_t)bc * HW;
    __shared__ float p5[3600];

    for (int cell = threadIdx.x; cell < 3600; cell += 256) {
        int pi = cell / 60, pj = cell % 60;
        const float* rp = xp + pi * 5 * WW + pj * 5;
        float s = 0.f;
#pragma unroll
        for (int u = 0; u < 5; u++)
#pragma unroll
            for (int v = 0; v < 5; v++) s += rp[u * WW + v];
        float m = s * 0.04f;
        p5[cell] = m;
        ws[OFF_P5 + bc * 3600 + cell] = m;
    }
    __syncthreads();
    for (int cell = threadIdx.x; cell < 900; cell += 256) {
        int pi = cell / 30, pj = cell % 30;
        float s = p5[(2 * pi) * 60 + 2 * pj] + p5[(2 * pi) * 60 + 2 * pj + 1] +
                  p5[(2 * pi + 1) * 60 + 2 * pj] + p5[(2 * pi + 1) * 60 + 2 * pj + 1];
        ws[OFF_P10 + bc * 900 + cell] = s * 0.25f;
    }
    for (int cell = threadIdx.x; cell < 400; cell += 256) {
        int pi = cell / 20, pj = cell % 20;
        float s = 0.f;
#pragma unroll
        for (int u = 0; u < 3; u++)
#pragma unroll
            for (int v = 0; v < 3; v++) s += p5[(3 * pi + u) * 60 + 3 * pj + v];
        ws[OFF_P15 + bc * 400 + cell] = s * (1.f / 9.f);
    }
}

// ---------------------------------------------------------------------------
// K2: fused  (concat -> conv_k)x3 -> concat -> gated conv -> y (pre-BN)
//     + per-channel partial sums for BN
// one block per 20x20 tile per batch; 256 threads
// ---------------------------------------------------------------------------
__global__ __launch_bounds__(256, 3) void k_fused(
    const float* __restrict__ x, const float* __restrict__ ws,
    const float* __restrict__ b5, const float* __restrict__ b10, const float* __restrict__ b15,
    const float* __restrict__ gb, const float* __restrict__ mb,
    float* __restrict__ out, double* __restrict__ stats) {
    __shared__ float xu[16][24][24];  // [0..7]=x halo2, [8..15]=upsampled halo2
    __shared__ float cs[8][22][22];   // c_k tile with halo1 (image-padding zeros applied)
    __shared__ float red[4][16];

    const int bx = blockIdx.x, by = blockIdx.y, b = blockIdx.z;
    const int r0 = by * TH, c0 = bx * TW;
    const int t = threadIdx.x;

    const float* xb = x + (size_t)b * CC * HW;

    // load x halo tile (zero outside image = conv padding)
    for (int idx = t; idx < 8 * 24 * 24; idx += 256) {
        int ch = idx / 576, rem = idx % 576, i = rem / 24, j = rem % 24;
        int r = r0 - 2 + i, c = c0 - 2 + j;
        float v = 0.f;
        if (r >= 0 && r < HH && c >= 0 && c < WW) v = xb[ch * HW + r * WW + c];
        xu[ch][i][j] = v;
    }

    // persistent gated-conv accumulators: 8 out-ch x (2 pixels) x (G,M)
    float gA0[8], gA1[8], mA0[8], mA1[8];
#pragma unroll
    for (int o = 0; o < 8; o++) { gA0[o] = 0.f; gA1[o] = 0.f; mA0[o] = 0.f; mA1[o] = 0.f; }

    const float* wA = ws + OFF_WA;
    const float* gwA = ws + OFF_GWA;
    const float* mwA = ws + OFF_MWA;

    // cs-phase pair mapping: 22x11 = 242 pairs (j even)
    const int cp_i = t / 11, cp_j = 2 * (t % 11);
    // gate-phase pair mapping: 20x10 = 200 pairs
    const int p_i = t / 10, p_j = 2 * (t % 10);

#pragma unroll 1
    for (int kk = 0; kk < 3; kk++) {
        const int kdiv = (kk == 0) ? 5 : ((kk == 1) ? 10 : 15);
        const int pw = (kk == 0) ? 60 : ((kk == 1) ? 30 : 20);
        const float* pooled = ws + ((kk == 0) ? OFF_P5 : ((kk == 1) ? OFF_P10 : OFF_P15));
        const float* bias = (kk == 0) ? b5 : ((kk == 1) ? b10 : b15);

        __syncthreads();  // prior iteration done reading cs/xu[8..]
        // load upsampled halo tile for this k
        for (int idx = t; idx < 8 * 24 * 24; idx += 256) {
            int ch = idx / 576, rem = idx % 576, i = rem / 24, j = rem % 24;
            int r = r0 - 2 + i, c = c0 - 2 + j;
            float v = 0.f;
            if (r >= 0 && r < HH && c >= 0 && c < WW)
                v = pooled[(b * 8 + ch) * pw * pw + (r / kdiv) * pw + (c / kdiv)];
            xu[8 + ch][i][j] = v;
        }
        __syncthreads();

        // compute c_k into cs: each active thread does 2 adjacent pixels, all 8 out-ch
        if (t < 242) {
            float a0[8], a1[8];
#pragma unroll
            for (int o = 0; o < 8; o++) { a0[o] = 0.f; a1[o] = 0.f; }
            const float* wk = wA + kk * 1152;
            for (int ci = 0; ci < 16; ci++) {
                const float* wu = wk + ci * 72;  // wave-uniform -> SGPR loads
                float v[3][4];
#pragma unroll
                for (int dr = 0; dr < 3; dr++)
#pragma unroll
                    for (int dc = 0; dc < 4; dc++) v[dr][dc] = xu[ci][cp_i + dr][cp_j + dc];
#pragma unroll
                for (int o = 0; o < 8; o++)
#pragma unroll
                    for (int dr = 0; dr < 3; dr++)
#pragma unroll
                        for (int dc = 0; dc < 3; dc++) {
                            float wv = wu[o * 9 + dr * 3 + dc];
                            a0[o] += v[dr][dc] * wv;
                            a1[o] += v[dr][dc + 1] * wv;
                        }
            }
            int r = r0 - 1 + cp_i;
            int c = c0 - 1 + cp_j;
            bool rok = (r >= 0 && r < HH);
            bool c0ok = rok && (c >= 0 && c < WW);
            bool c1ok = rok && (c + 1 >= 0 && c + 1 < WW);
#pragma unroll
            for (int o = 0; o < 8; o++) {
                float bo = bias[o];
                cs[o][cp_i][cp_j] = c0ok ? (a0[o] + bo) : 0.f;
                cs[o][cp_i][cp_j + 1] = c1ok ? (a1[o] + bo) : 0.f;
            }
        }
        __syncthreads();

        // accumulate gated-conv contribution of this k-group
        if (t < 200) {
            for (int ci = 0; ci < 8; ci++) {
                const float* gu = gwA + (kk * 8 + ci) * 72;  // wave-uniform
                const float* mu = mwA + (kk * 8 + ci) * 72;
                float v[3][4];
#pragma unroll
                for (int dr = 0; dr < 3; dr++)
#pragma unroll
                    for (int dc = 0; dc < 4; dc++) v[dr][dc] = cs[ci][p_i + dr][p_j + dc];
#pragma unroll
                for (int o = 0; o < 8; o++)
#pragma unroll
                    for (int dr = 0; dr < 3; dr++)
#pragma unroll
                        for (int dc = 0; dc < 3; dc++) {
                            float gv = gu[o * 9 + dr * 3 + dc];
                            float mv = mu[o * 9 + dr * 3 + dc];
                            gA0[o] += v[dr][dc] * gv;
                            gA1[o] += v[dr][dc + 1] * gv;
                            mA0[o] += v[dr][dc] * mv;
                            mA1[o] += v[dr][dc + 1] * mv;
                        }
            }
        }
    }

    // epilogue: gate, store pre-BN y, per-channel partial sums
    float ls[8], ls2[8];
#pragma unroll
    for (int o = 0; o < 8; o++) { ls[o] = 0.f; ls2[o] = 0.f; }
    if (t < 200) {
        int r = r0 + p_i, c = c0 + p_j;
#pragma unroll
        for (int o = 0; o < 8; o++) {
            float gbo = gb[o], mbo = mb[o];
            float g0 = gA0[o] + gbo, m0 = mA0[o] + mbo;
            float g1 = gA1[o] + gbo, m1 = mA1[o] + mbo;
            float y0 = g0 / (1.f + expf(-m0));
            float y1 = g1 / (1.f + expf(-m1));
            size_t base = (size_t)(b * 8 + o) * HW + r * WW + c;
            out[base] = y0;
            out[base + 1] = y1;
            ls[o] = y0 + y1;
            ls2[o] = y0 * y0 + y1 * y1;
        }
    }
    // wave -> block -> hashed-bin global reduction
#pragma unroll
    for (int o = 0; o < 8; o++) {
        float s1 = ls[o], s2 = ls2[o];
#pragma unroll
        for (int off = 32; off > 0; off >>= 1) {
            s1 += __shfl_down(s1, off);
            s2 += __shfl_down(s2, off);
        }
        if ((t & 63) == 0) {
            red[t >> 6][o] = s1;
            red[t >> 6][8 + o] = s2;
        }
    }
    __syncthreads();
    if (t < 16) {
        float s = red[0][t] + red[1][t] + red[2][t] + red[3][t];
        int hash = (blockIdx.x + 15 * blockIdx.y + 225 * blockIdx.z) & 63;
        atomicAdd(&stats[t * 64 + hash], (double)s);
    }
}

// ---------------------------------------------------------------------------
// K3: finalize BN stats -> per-channel scale/shift
// ---------------------------------------------------------------------------
__global__ void k_stats(const double* __restrict__ stats, const float* __restrict__ gamma,
                        const float* __restrict__ beta, float* __restrict__ ss) {
    __shared__ double tot[16];
    int t = threadIdx.x;
    if (t < 16) {
        double s = 0.0;
        for (int i = 0; i < 64; i++) s += stats[t * 64 + i];
        tot[t] = s;
    }
    __syncthreads();
    if (t < 8) {
        double N = (double)NPX;
        double mean = tot[t] / N;
        double var = tot[8 + t] / N - mean * mean;
        double scale = (double)gamma[t] / sqrt(var + 1e-5);
        ss[t] = (float)scale;
        ss[8 + t] = (float)((double)beta[t] - mean * scale);
    }
}

// ---------------------------------------------------------------------------
// K4: in-place normalize  out = out*scale[c] + shift[c]
// ---------------------------------------------------------------------------
__global__ void k_norm(float* __restrict__ out, const float* __restrict__ ss) {
    int i = blockIdx.x * 256 + threadIdx.x;  // float4 index
    if (i < (BN * CC * HW) / 4) {
        int plane = (i * 4) / HW;
        int ch = plane & 7;
        float sc = ss[ch], sh = ss[8 + ch];
        float4* p = (float4*)out + i;
        float4 v = *p;
        v.x = v.x * sc + sh;
        v.y = v.y * sc + sh;
        v.z = v.z * sc + sh;
        v.w = v.w * sc + sh;
        *p = v;
    }
}

// ---------------------------------------------------------------------------
extern "C" void kernel_launch(void* const* d_in, const int* in_sizes, int n_in,
                              void* d_out, int out_size, void* d_ws, size_t ws_size,
                              hipStream_t stream) {
    const float* x = (const float*)d_in[0];
    const float* w5 = (const float*)d_in[1];
    const float* b5 = (const float*)d_in[2];
    const float* w10 = (const float*)d_in[3];
    const float* b10 = (const float*)d_in[4];
    const float* w15 = (const float*)d_in[5];
    const float* b15 = (const float*)d_in[6];
    const float* gw = (const float*)d_in[7];
    const float* gb = (const float*)d_in[8];
    const float* mw = (const float*)d_in[9];
    const float* mb = (const float*)d_in[10];
    const float* gamma = (const float*)d_in[11];
    const float* beta = (const float*)d_in[12];

    float* out = (float*)d_out;
    float* ws = (float*)d_ws;
    double* stats = (double*)((char*)d_ws + STAT_BYTE_OFF);
    float* ss = (float*)((char*)d_ws + SS_BYTE_OFF);

    k_setup<<<1, 256, 0, stream>>>(w5, w10, w15, gw, mw, ws, stats);
    k_pool<<<BN * CC, 256, 0, stream>>>(x, ws);
    dim3 grid(NTX, NTY, BN);
    k_fused<<<grid, 256, 0, stream>>>(x, ws, b5, b10, b15, gb, mb, out, stats);
    k_stats<<<1, 64, 0, stream>>>(stats, gamma, beta, ss);
    k_norm<<<(BN * CC * HW / 4 + 255) / 256, 256, 0, stream>>>(out, ss);
}

// Round 2
// 975.979 us; speedup vs baseline: 1.4033x; 1.4033x over previous
//
#include <hip/hip_runtime.h>
#include <math.h>

// Problem constants
#define BN 32
#define CC 8
#define HH 300
#define WW 300
#define HW 90000            // 300*300
#define NPX (BN * HW)       // per-channel pixel count for BN: 32*90000 = 2,880,000

// Tiling for fused kernel
#define TH 20
#define TW 20
#define NTY 15
#define NTX 15

// Workspace layout (float offsets)
#define OFF_P5   0              // [32][8][60*60]  = 921600 floats
#define OFF_P10  921600         // [32][8][30*30]  = 230400
#define OFF_P15  1152000        // [32][8][20*20]  = 102400
#define OFF_WA   1254400        // [3][16][8][9]   = 3456   (w5/w10/w15 rearranged [kk][ci][o][tap])
#define OFF_GWA  1257856        // [24][8][9]      = 1728   (gw rearranged [ci24][o][tap])
#define OFF_MWA  1259584        // [24][8][9]      = 1728
#define FLOATS_END 1261312
#define STAT_BYTE_OFF  5045248  // = FLOATS_END*4, 8B aligned; [16][64] doubles = 8192 B
#define SS_BYTE_OFF    5053440  // 16 floats: scale[8], shift[8]

// ---------------------------------------------------------------------------
// K0: rearrange weights for wave-uniform (SGPR) access + zero BN stat bins
// ---------------------------------------------------------------------------
__global__ void k_setup(const float* __restrict__ w5, const float* __restrict__ w10,
                        const float* __restrict__ w15, const float* __restrict__ gw,
                        const float* __restrict__ mw, float* __restrict__ ws,
                        double* __restrict__ stats) {
    int t = threadIdx.x;
    for (int idx = t; idx < 3 * 16 * 8 * 9; idx += 256) {
        int kk = idx / 1152;
        int rem = idx % 1152;
        int ci = rem / 72;
        int r2 = rem % 72;
        int o = r2 / 9;
        int tap = r2 % 9;
        const float* src = (kk == 0) ? w5 : ((kk == 1) ? w10 : w15);
        ws[OFF_WA + idx] = src[(o * 16 + ci) * 9 + tap];
    }
    for (int idx = t; idx < 24 * 72; idx += 256) {
        int kc = idx / 72;
        int r2 = idx % 72;
        int o = r2 / 9;
        int tap = r2 % 9;
        ws[OFF_GWA + idx] = gw[(o * 24 + kc) * 9 + tap];
        ws[OFF_MWA + idx] = mw[(o * 24 + kc) * 9 + tap];
    }
    for (int idx = t; idx < 16 * 64; idx += 256) stats[idx] = 0.0;
}

// ---------------------------------------------------------------------------
// K1: adaptive-avg-pool to 60x60 (k=5), then derive 30x30 (k=10), 20x20 (k=15)
// ---------------------------------------------------------------------------
__global__ void k_pool(const float* __restrict__ x, float* __restrict__ ws) {
    int bc = blockIdx.x;  // 0..255 = b*8+c
    const float* xp = x + (size_t)bc * HW;
    __shared__ float p5[3600];

    for (int cell = threadIdx.x; cell < 3600; cell += 256) {
        int pi = cell / 60, pj = cell % 60;
        const float* rp = xp + pi * 5 * WW + pj * 5;
        float s = 0.f;
#pragma unroll
        for (int u = 0; u < 5; u++)
#pragma unroll
            for (int v = 0; v < 5; v++) s += rp[u * WW + v];
        float m = s * 0.04f;
        p5[cell] = m;
        ws[OFF_P5 + bc * 3600 + cell] = m;
    }
    __syncthreads();
    for (int cell = threadIdx.x; cell < 900; cell += 256) {
        int pi = cell / 30, pj = cell % 30;
        float s = p5[(2 * pi) * 60 + 2 * pj] + p5[(2 * pi) * 60 + 2 * pj + 1] +
                  p5[(2 * pi + 1) * 60 + 2 * pj] + p5[(2 * pi + 1) * 60 + 2 * pj + 1];
        ws[OFF_P10 + bc * 900 + cell] = s * 0.25f;
    }
    for (int cell = threadIdx.x; cell < 400; cell += 256) {
        int pi = cell / 20, pj = cell % 20;
        float s = 0.f;
#pragma unroll
        for (int u = 0; u < 3; u++)
#pragma unroll
            for (int v = 0; v < 3; v++) s += p5[(3 * pi + u) * 60 + 3 * pj + v];
        ws[OFF_P15 + bc * 400 + cell] = s * (1.f / 9.f);
    }
}

// ---------------------------------------------------------------------------
// per-scale body of the fused kernel, K = pool factor (compile-time constant
// so the /K become magic-muls). Reads up-values straight from pooled cells
// (piecewise-constant upsample => no upsampled halo staging needed).
// ---------------------------------------------------------------------------
template <int K, int PW, int NC>
__device__ __forceinline__ void do_kk(
    float xs[8][24][25], float cs[8][22][23], float pc[8][36],
    const float* __restrict__ pooled, const float* __restrict__ bias,
    const float* __restrict__ wk,   // [16][8][9] this scale
    const float* __restrict__ gwk,  // [8][8][9]  this scale's slice of gw
    const float* __restrict__ mwk,
    int b, int r0, int c0, int t, int cp_i, int cp_j, int p_i, int p_j,
    float* gA0, float* gA1, float* mA0, float* mA1) {
    const int cr0 = (int)((unsigned)(r0 - 2 + 60) / K) - 60 / K;
    const int cc0 = (int)((unsigned)(c0 - 2 + 60) / K) - 60 / K;

    __syncthreads();  // prev c-phase done with pc, prev gate done with cs
    // stage pooled cells covering tile+halo: NC x NC x 8ch (<= 288 floats)
    for (int idx = t; idx < 8 * NC * NC; idx += 256) {
        int ch = idx / (NC * NC), rem = idx % (NC * NC);
        int i = rem / NC, j = rem % NC;
        int pi = cr0 + i, pj = cc0 + j;
        float v = 0.f;
        if (pi >= 0 && pi < PW && pj >= 0 && pj < PW)
            v = pooled[(size_t)(b * 8 + ch) * (PW * PW) + pi * PW + pj];
        pc[ch][rem] = v;
    }
    __syncthreads();

    // c-phase: conv([x, up_k]) -> cs (22x22, 2 px/thread)
    if (t < 242) {
        const int r = r0 - 1 + cp_i;
        const int c = c0 - 1 + cp_j;
        float a0[8], a1[8];
#pragma unroll
        for (int o = 0; o < 8; o++) { a0[o] = 0.f; a1[o] = 0.f; }
        // x channels 0..7 from xs
        for (int ci = 0; ci < 8; ci++) {
            const float* wu = wk + ci * 72;  // wave-uniform -> SGPR
            float v[3][4];
#pragma unroll
            for (int dr = 0; dr < 3; dr++)
#pragma unroll
                for (int dc = 0; dc < 4; dc++) v[dr][dc] = xs[ci][cp_i + dr][cp_j + dc];
#pragma unroll
            for (int o = 0; o < 8; o++)
#pragma unroll
                for (int dr = 0; dr < 3; dr++)
#pragma unroll
                    for (int dc = 0; dc < 3; dc++) {
                        float wv = wu[o * 9 + dr * 3 + dc];
                        a0[o] += v[dr][dc] * wv;
                        a1[o] += v[dr][dc + 1] * wv;
                    }
        }
        // up channels 8..15: values read from pooled cells (exact upsample)
        int roff[3], coff[4];
#pragma unroll
        for (int dr = 0; dr < 3; dr++)
            roff[dr] = ((int)((unsigned)(r - 1 + dr + 60) / K) - 60 / K - cr0) * NC;
#pragma unroll
        for (int dc = 0; dc < 4; dc++)
            coff[dc] = (int)((unsigned)(c - 1 + dc + 60) / K) - 60 / K - cc0;
        for (int ci = 0; ci < 8; ci++) {
            const float* wu = wk + (8 + ci) * 72;
            float v[3][4];
#pragma unroll
            for (int dr = 0; dr < 3; dr++)
#pragma unroll
                for (int dc = 0; dc < 4; dc++) v[dr][dc] = pc[ci][roff[dr] + coff[dc]];
#pragma unroll
            for (int o = 0; o < 8; o++)
#pragma unroll
                for (int dr = 0; dr < 3; dr++)
#pragma unroll
                    for (int dc = 0; dc < 3; dc++) {
                        float wv = wu[o * 9 + dr * 3 + dc];
                        a0[o] += v[dr][dc] * wv;
                        a1[o] += v[dr][dc + 1] * wv;
                    }
        }
        bool rok = (r >= 0 && r < HH);
        bool c0ok = rok && (c >= 0 && c < WW);
        bool c1ok = rok && (c + 1 >= 0 && c + 1 < WW);
#pragma unroll
        for (int o = 0; o < 8; o++) {
            float bo = bias[o];
            cs[o][cp_i][cp_j] = c0ok ? (a0[o] + bo) : 0.f;
            cs[o][cp_i][cp_j + 1] = c1ok ? (a1[o] + bo) : 0.f;
        }
    }
    __syncthreads();

    // gate-phase: accumulate this scale's 8 channels of g_in into G/M accums
    if (t < 200) {
        for (int ci = 0; ci < 8; ci++) {
            const float* gu = gwk + ci * 72;
            const float* mu = mwk + ci * 72;
            float v[3][4];
#pragma unroll
            for (int dr = 0; dr < 3; dr++)
#pragma unroll
                for (int dc = 0; dc < 4; dc++) v[dr][dc] = cs[ci][p_i + dr][p_j + dc];
#pragma unroll
            for (int o = 0; o < 8; o++)
#pragma unroll
                for (int dr = 0; dr < 3; dr++)
#pragma unroll
                    for (int dc = 0; dc < 3; dc++) {
                        float gv = gu[o * 9 + dr * 3 + dc];
                        float mv = mu[o * 9 + dr * 3 + dc];
                        gA0[o] += v[dr][dc] * gv;
                        gA1[o] += v[dr][dc + 1] * gv;
                        mA0[o] += v[dr][dc] * mv;
                        mA1[o] += v[dr][dc + 1] * mv;
                    }
        }
    }
}

// ---------------------------------------------------------------------------
// K2: fused  (concat -> conv_k)x3 -> concat -> gated conv -> y (pre-BN)
// ---------------------------------------------------------------------------
__global__ __launch_bounds__(256, 4) void k_fused(
    const float* __restrict__ x, const float* __restrict__ ws,
    const float* __restrict__ b5, const float* __restrict__ b10, const float* __restrict__ b15,
    const float* __restrict__ gb, const float* __restrict__ mb,
    float* __restrict__ out, double* __restrict__ stats) {
    __shared__ float xs[8][24][25];  // x halo2, padded stride
    __shared__ float cs[8][22][23];  // c_k tile halo1, padded stride
    __shared__ float pc[8][36];      // pooled cells for current scale
    __shared__ float red[4][16];

    const int bx = blockIdx.x, by = blockIdx.y, b = blockIdx.z;
    const int r0 = by * TH, c0 = bx * TW;
    const int t = threadIdx.x;

    const float* xb = x + (size_t)b * CC * HW;

    // stage x halo tile once (zero outside image = conv padding)
    for (int idx = t; idx < 8 * 576; idx += 256) {
        int ch = idx / 576, rem = idx % 576, i = rem / 24, j = rem % 24;
        int r = r0 - 2 + i, c = c0 - 2 + j;
        float v = 0.f;
        if (r >= 0 && r < HH && c >= 0 && c < WW) v = xb[ch * HW + r * WW + c];
        xs[ch][i][j] = v;
    }

    float gA0[8], gA1[8], mA0[8], mA1[8];
#pragma unroll
    for (int o = 0; o < 8; o++) { gA0[o] = 0.f; gA1[o] = 0.f; mA0[o] = 0.f; mA1[o] = 0.f; }

    const float* wA = ws + OFF_WA;
    const float* gwA = ws + OFF_GWA;
    const float* mwA = ws + OFF_MWA;

    const int cp_i = t / 11, cp_j = 2 * (t % 11);  // 242 pairs cover 22x22
    const int p_i = t / 10, p_j = 2 * (t % 10);    // 200 pairs cover 20x20

    do_kk<5, 60, 6>(xs, cs, pc, ws + OFF_P5, b5, wA, gwA, mwA,
                    b, r0, c0, t, cp_i, cp_j, p_i, p_j, gA0, gA1, mA0, mA1);
    do_kk<10, 30, 4>(xs, cs, pc, ws + OFF_P10, b10, wA + 1152, gwA + 576, mwA + 576,
                     b, r0, c0, t, cp_i, cp_j, p_i, p_j, gA0, gA1, mA0, mA1);
    do_kk<15, 20, 3>(xs, cs, pc, ws + OFF_P15, b15, wA + 2304, gwA + 1152, mwA + 1152,
                     b, r0, c0, t, cp_i, cp_j, p_i, p_j, gA0, gA1, mA0, mA1);

    // epilogue: gate, store pre-BN y, per-channel partial sums
    float ls[8], ls2[8];
#pragma unroll
    for (int o = 0; o < 8; o++) { ls[o] = 0.f; ls2[o] = 0.f; }
    if (t < 200) {
        int r = r0 + p_i, c = c0 + p_j;
#pragma unroll
        for (int o = 0; o < 8; o++) {
            float gbo = gb[o], mbo = mb[o];
            float g0 = gA0[o] + gbo, m0 = mA0[o] + mbo;
            float g1 = gA1[o] + gbo, m1 = mA1[o] + mbo;
            float y0 = g0 / (1.f + expf(-m0));
            float y1 = g1 / (1.f + expf(-m1));
            size_t base = (size_t)(b * 8 + o) * HW + r * WW + c;
            out[base] = y0;
            out[base + 1] = y1;
            ls[o] = y0 + y1;
            ls2[o] = y0 * y0 + y1 * y1;
        }
    }
#pragma unroll
    for (int o = 0; o < 8; o++) {
        float s1 = ls[o], s2 = ls2[o];
#pragma unroll
        for (int off = 32; off > 0; off >>= 1) {
            s1 += __shfl_down(s1, off);
            s2 += __shfl_down(s2, off);
        }
        if ((t & 63) == 0) {
            red[t >> 6][o] = s1;
            red[t >> 6][8 + o] = s2;
        }
    }
    __syncthreads();
    if (t < 16) {
        float s = red[0][t] + red[1][t] + red[2][t] + red[3][t];
        int hash = (blockIdx.x + 15 * blockIdx.y + 225 * blockIdx.z) & 63;
        atomicAdd(&stats[t * 64 + hash], (double)s);
    }
}

// ---------------------------------------------------------------------------
// K3: finalize BN stats -> per-channel scale/shift
// ---------------------------------------------------------------------------
__global__ void k_stats(const double* __restrict__ stats, const float* __restrict__ gamma,
                        const float* __restrict__ beta, float* __restrict__ ss) {
    __shared__ double tot[16];
    int t = threadIdx.x;
    if (t < 16) {
        double s = 0.0;
        for (int i = 0; i < 64; i++) s += stats[t * 64 + i];
        tot[t] = s;
    }
    __syncthreads();
    if (t < 8) {
        double N = (double)NPX;
        double mean = tot[t] / N;
        double var = tot[8 + t] / N - mean * mean;
        double scale = (double)gamma[t] / sqrt(var + 1e-5);
        ss[t] = (float)scale;
        ss[8 + t] = (float)((double)beta[t] - mean * scale);
    }
}

// ---------------------------------------------------------------------------
// K4: in-place normalize  out = out*scale[c] + shift[c]
// ---------------------------------------------------------------------------
__global__ void k_norm(float* __restrict__ out, const float* __restrict__ ss) {
    int i = blockIdx.x * 256 + threadIdx.x;  // float4 index
    if (i < (BN * CC * HW) / 4) {
        int plane = (i * 4) / HW;
        int ch = plane & 7;
        float sc = ss[ch], sh = ss[8 + ch];
        float4* p = (float4*)out + i;
        float4 v = *p;
        v.x = v.x * sc + sh;
        v.y = v.y * sc + sh;
        v.z = v.z * sc + sh;
        v.w = v.w * sc + sh;
        *p = v;
    }
}

// ---------------------------------------------------------------------------
extern "C" void kernel_launch(void* const* d_in, const int* in_sizes, int n_in,
                              void* d_out, int out_size, void* d_ws, size_t ws_size,
                              hipStream_t stream) {
    const float* x = (const float*)d_in[0];
    const float* w5 = (const float*)d_in[1];
    const float* b5 = (const float*)d_in[2];
    const float* w10 = (const float*)d_in[3];
    const float* b10 = (const float*)d_in[4];
    const float* w15 = (const float*)d_in[5];
    const float* b15 = (const float*)d_in[6];
    const float* gw = (const float*)d_in[7];
    const float* gb = (const float*)d_in[8];
    const float* mw = (const float*)d_in[9];
    const float* mb = (const float*)d_in[10];
    const float* gamma = (const float*)d_in[11];
    const float* beta = (const float*)d_in[12];

    float* out = (float*)d_out;
    float* ws = (float*)d_ws;
    double* stats = (double*)((char*)d_ws + STAT_BYTE_OFF);
    float* ss = (float*)((char*)d_ws + SS_BYTE_OFF);

    k_setup<<<1, 256, 0, stream>>>(w5, w10, w15, gw, mw, ws, stats);
    k_pool<<<BN * CC, 256, 0, stream>>>(x, ws);
    dim3 grid(NTX, NTY, BN);
    k_fused<<<grid, 256, 0, stream>>>(x, ws, b5, b10, b15, gb, mb, out, stats);
    k_stats<<<1, 64, 0, stream>>>(stats, gamma, beta, ss);
    k_norm<<<(BN * CC * HW / 4 + 255) / 256, 256, 0, stream>>>(out, ss);
}